// Round 6
// baseline (2110.390 us; speedup 1.0000x reference)
//
#include <hip/hip_runtime.h>
#include <stdint.h>

// FPS: B=32 batches, P=131072 points, S=512 samples.
// 32 batches x 8 groups, 1024 threads/wg, 16 points/thread.
// Points AND running min-dists in VGPRs (waves_per_eu(4,4) => 128-reg budget;
// demand ~90). NO __syncthreads in the step loop:
//   - each wave's lane0 atomically stores its self-tagged combo
//     [distbits:32][tag:10][~idx:17] to LDS slot sk[parity][wave]
//   - wave0 polls the 16 LDS slots until all carry this step's tag, reduces,
//     lane0 publishes group combo to the batch's global 64B record line
//   - ALL waves poll the 8 group records (lanes 0-7, relaxed; combos are
//     self-contained so no fences), reduce, broadcast, fetch winner coords.
// Overwrite safety (LDS slots and global records, both parity-dbuffered):
// slot for step s+2 is only written after its writer passed the step-s+1
// poll, which implies every reader of the step-s slot already finished.

#define BATCHES 32
#define THREADS 1024
#define GROUPS  8
#define KPT     16            // P / (GROUPS*THREADS)
#define NWAVES  (THREADS / 64)
#define IDX_MASK 0x1FFFFu     // 17 bits: P=131072
#define TAG_SHIFT 22
#define TAG_MASK 0x3FFu       // tags 1..512; 0xAA-poison tag=682 never matches
#define LINE_U64 16           // 128B per (batch,parity) record line

__global__ void init_ws_kernel(uint64_t* cand) {
  cand[threadIdx.x] = 0ull;   // BATCHES*2*LINE_U64 = 1024 exactly (tag=0)
}

__global__ __attribute__((amdgpu_flat_work_group_size(THREADS, THREADS),
                          amdgpu_waves_per_eu(4, 4)))
void fps_kernel(const float* __restrict__ points,
                const int* __restrict__ nsamp_p,
                float* __restrict__ out,
                uint64_t* __restrict__ cand,
                int P) {
#pragma clang fp contract(off)
  // linear id % 8 == batch % 8: all 8 groups of a batch on one XCD (heuristic)
  const int l = blockIdx.x;
  const int m = l >> 3;
  const int b = (l & 7) + ((m & 3) << 3);   // batch
  const int g = m >> 2;                     // group within batch
  const int t = threadIdx.x;
  const int lane = t & 63;
  const int w = t >> 6;
  const int S = nsamp_p[0];
  const int base = g * (P / GROUPS);
  const float* pb = points + (size_t)b * P * 3;

  __shared__ uint64_t sk[2][NWAVES];        // self-tagged wave combos

  // This thread's 16 points + running min-dists, all in registers.
  float px[KPT], py[KPT], pz[KPT], dist[KPT];
#pragma unroll
  for (int k = 0; k < KPT; ++k) {
    int p = base + t + k * THREADS;
    px[k] = pb[(size_t)p * 3 + 0];
    py[k] = pb[(size_t)p * 3 + 1];
    pz[k] = pb[(size_t)p * 3 + 2];
    dist[k] = __builtin_inff();
  }
  if (lane == 0) {  // own-slot init (tag=0); single writer, so no race
    __hip_atomic_store(&sk[0][w], 0ull, __ATOMIC_RELAXED, __HIP_MEMORY_SCOPE_WORKGROUP);
    __hip_atomic_store(&sk[1][w], 0ull, __ATOMIC_RELAXED, __HIP_MEMORY_SCOPE_WORKGROUP);
  }

  // Wave-carried current state (wave-uniform registers).
  int cur = 0;                 // reference always starts at index 0
  float cx = pb[0], cy = pb[1], cz = pb[2];

  float* out_idx = out;                        // [B][S] indices as f32
  float* out_pts = out + (size_t)BATCHES * S;  // [B][S][3]
  uint64_t* line_base = cand + (size_t)b * 2 * LINE_U64;

  for (int s = 0; s < S; ++s) {
    const uint32_t tag = (uint32_t)(s + 1);
    const int par = s & 1;

    // ---- update running min-dists; per-thread (max dist, first index) ----
    float bd = -1.0f;
    int bi = 0;
#pragma unroll
    for (int k = 0; k < KPT; ++k) {
      float dx = px[k] - cx;
      float dy = py[k] - cy;
      float dz = pz[k] - cz;
      float d = (dx * dx + dy * dy) + dz * dz;   // numpy order, no FMA
      float nd = dist[k] < d ? dist[k] : d;      // jnp.minimum
      dist[k] = nd;
      if (nd > bd) { bd = nd; bi = base + t + k * THREADS; }  // k asc => first-max
    }

    // ---- two-phase wave reduce: max distbits, then max ~idx among tied ----
    const uint32_t mydb = __float_as_uint(bd);   // bd >= 0 => order-preserving
    uint32_t db = mydb;
#pragma unroll
    for (int off = 1; off < 64; off <<= 1) {
      uint32_t o = __shfl_xor(db, off, 64);
      db = o > db ? o : db;
    }
    uint32_t mk = (mydb == db) ? ~(uint32_t)bi : 0u;
#pragma unroll
    for (int off = 1; off < 64; off <<= 1) {
      uint32_t o = __shfl_xor(mk, off, 64);
      mk = o > mk ? o : mk;
    }

    if (lane == 0) {
      unsigned long long combo = ((unsigned long long)db << 32) |
                                 ((unsigned long long)tag << TAG_SHIFT) |
                                 (unsigned long long)(mk & IDX_MASK);
      __hip_atomic_store(&sk[par][w], combo, __ATOMIC_RELAXED,
                         __HIP_MEMORY_SCOPE_WORKGROUP);
    }

    uint64_t* line = line_base + (size_t)par * LINE_U64;

    if (w == 0) {
      // wave0: poll the 16 LDS slots until all carry this step's tag.
      unsigned long long v = 0;
      int done = (lane < NWAVES) ? 0 : 1;
      while (!__all(done)) {
        if (!done) {
          v = __hip_atomic_load(&sk[par][lane], __ATOMIC_RELAXED,
                                __HIP_MEMORY_SCOPE_WORKGROUP);
          done = (((uint32_t)(v >> TAG_SHIFT) & TAG_MASK) == tag);
        }
      }
      // reduce 16 combos (lanes 0-15; others hold 0)
#pragma unroll
      for (int off = 1; off < NWAVES; off <<= 1) {
        unsigned long long o = __shfl_xor(v, off, 64);
        if (o > v) v = o;
      }
      if (lane == 0) {
        __hip_atomic_store(&line[g], v, __ATOMIC_RELAXED,
                           __HIP_MEMORY_SCOPE_AGENT);
        if (g == 0) {   // after publish: off the critical path
          out_idx[(size_t)b * S + s] = (float)cur;
          size_t o = ((size_t)b * S + s) * 3;
          out_pts[o + 0] = cx; out_pts[o + 1] = cy; out_pts[o + 2] = cz;
        }
      }
    }

    // ---- all waves poll the 8 group records (relaxed, self-contained) ----
    unsigned long long v = 0;
    int done = (lane < GROUPS) ? 0 : 1;
    while (!__all(done)) {
      if (!done) {
        v = __hip_atomic_load(&line[lane], __ATOMIC_RELAXED,
                              __HIP_MEMORY_SCOPE_AGENT);
        done = (((uint32_t)(v >> TAG_SHIFT) & TAG_MASK) == tag);
      }
      if (!__all(done)) __builtin_amdgcn_s_sleep(1);
    }
#pragma unroll
    for (int off = 1; off < GROUPS; off <<= 1) {
      unsigned long long o = __shfl_xor(v, off, 64);
      if (o > v) v = o;
    }
    v = __shfl(v, 0, 64);      // broadcast lane0's result to all lanes

    // ---- winner index + coords (uniform-address load, one txn per wave) ----
    cur = (int)((~(uint32_t)v) & IDX_MASK);
    const float* wp = pb + (size_t)cur * 3;
    cx = wp[0]; cy = wp[1]; cz = wp[2];
  }
}

extern "C" void kernel_launch(void* const* d_in, const int* in_sizes, int n_in,
                              void* d_out, int out_size, void* d_ws, size_t ws_size,
                              hipStream_t stream) {
  const float* points = (const float*)d_in[0];
  const int* nsamples = (const int*)d_in[1];
  // d_in[2] = kd_depth: acceleration parameter only; math identical. Ignored.

  const int P = in_sizes[0] / (BATCHES * 3);   // 131072

  uint64_t* cand = (uint64_t*)d_ws;   // [32][2][16 u64] = 8KB

  hipLaunchKernelGGL(init_ws_kernel, dim3(1), dim3(BATCHES * 2 * LINE_U64),
                     0, stream, cand);

  dim3 grid(GROUPS * BATCHES);
  hipLaunchKernelGGL(fps_kernel, grid, dim3(THREADS), 0, stream,
                     points, nsamples, (float*)d_out, cand, P);
}

// Round 7
// 1356.700 us; speedup vs baseline: 1.5555x; 1.5555x over previous
//
#include <hip/hip_runtime.h>
#include <stdint.h>

// FPS: B=32 batches, P=131072 points, S=512 samples.
// 32 batches x 8 groups, 1024 threads/wg, 16 points/thread.
// Structure = round-5 (verified): points in VGPRs, running min-dists in LDS
// thread-private slots, ONE __syncthreads per step, self-tagged 8B global
// records [distbits:32][tag:10][~idx:17], parity-double-buffered.
// Round-7 change: ALL cross-lane reduces use DPP v_max_u32 chains (VALU pipe,
// ~2cy/op) instead of __shfl_xor (ds_bpermute, ~100cy dependent chain), and
// readlane(63) broadcasts instead of a final shfl.

#define BATCHES 32
#define THREADS 1024
#define GROUPS  8
#define KPT     16            // P / (GROUPS*THREADS)
#define NWAVES  (THREADS / 64)
#define IDX_MASK 0x1FFFFu     // 17 bits: P=131072
#define TAG_SHIFT 22
#define TAG_MASK 0x3FFu       // tags 1..512; 0xAA-poison tag=682 never matches
#define LINE_U64 16           // 128B per (batch,parity) record line

// Full-wave (64-lane) max reduce in the VALU pipe. Valid result in lane 63;
// all inputs must be >= 0-neutral (u32). bound_ctrl:0 => OOB lanes read 0.
__device__ __forceinline__ uint32_t dpp_wave_max(uint32_t v) {
  uint32_t o;
  o = (uint32_t)__builtin_amdgcn_update_dpp(0, (int)v, 0x111, 0xf, 0xf, true); // row_shr:1
  v = o > v ? o : v;
  o = (uint32_t)__builtin_amdgcn_update_dpp(0, (int)v, 0x112, 0xf, 0xf, true); // row_shr:2
  v = o > v ? o : v;
  o = (uint32_t)__builtin_amdgcn_update_dpp(0, (int)v, 0x114, 0xf, 0xf, true); // row_shr:4
  v = o > v ? o : v;
  o = (uint32_t)__builtin_amdgcn_update_dpp(0, (int)v, 0x118, 0xf, 0xf, true); // row_shr:8
  v = o > v ? o : v;
  o = (uint32_t)__builtin_amdgcn_update_dpp(0, (int)v, 0x142, 0xa, 0xf, true); // row_bcast:15
  v = o > v ? o : v;
  o = (uint32_t)__builtin_amdgcn_update_dpp(0, (int)v, 0x143, 0xc, 0xf, true); // row_bcast:31
  v = o > v ? o : v;
  return v;   // lane 63 holds the wave max
}

__device__ __forceinline__ uint32_t wave_max_bcast(uint32_t v) {
  return (uint32_t)__builtin_amdgcn_readlane((int)dpp_wave_max(v), 63);
}

__global__ void init_ws_kernel(uint64_t* cand) {
  cand[threadIdx.x] = 0ull;   // BATCHES*2*LINE_U64 = 1024 exactly (tag=0)
}

__global__ __attribute__((amdgpu_flat_work_group_size(THREADS, THREADS),
                          amdgpu_waves_per_eu(4, 4)))
void fps_kernel(const float* __restrict__ points,
                const int* __restrict__ nsamp_p,
                float* __restrict__ out,
                uint64_t* __restrict__ cand,
                int P) {
#pragma clang fp contract(off)
  // linear id % 8 == batch % 8: all 8 groups of a batch on one XCD (heuristic)
  const int l = blockIdx.x;
  const int m = l >> 3;
  const int b = (l & 7) + ((m & 3) << 3);   // batch
  const int g = m >> 2;                     // group within batch
  const int t = threadIdx.x;
  const int lane = t & 63;
  const int w = t >> 6;
  const int S = nsamp_p[0];
  const int base = g * (P / GROUPS);
  const float* pb = points + (size_t)b * P * 3;

  __shared__ float sdist[KPT * THREADS];    // thread-private slots, 2-way banks (free)
  __shared__ uint64_t sk[2][NWAVES];        // per-wave combos, parity dbuf

  // This thread's 16 points into registers; dists to LDS (+inf).
  float px[KPT], py[KPT], pz[KPT];
#pragma unroll
  for (int k = 0; k < KPT; ++k) {
    int p = base + t + k * THREADS;
    px[k] = pb[(size_t)p * 3 + 0];
    py[k] = pb[(size_t)p * 3 + 1];
    pz[k] = pb[(size_t)p * 3 + 2];
    sdist[k * THREADS + t] = __builtin_inff();
  }

  // Wave-carried current state (wave-uniform registers).
  int cur = 0;                 // reference always starts at index 0
  float cx = pb[0], cy = pb[1], cz = pb[2];

  float* out_idx = out;                        // [B][S] indices as f32
  float* out_pts = out + (size_t)BATCHES * S;  // [B][S][3]
  uint64_t* line_base = cand + (size_t)b * 2 * LINE_U64;

  for (int s = 0; s < S; ++s) {
    const uint32_t tag = (uint32_t)(s + 1);
    const int par = s & 1;

    // ---- update running min-dists; per-thread (max dist, first index) ----
    float bd = -1.0f;
    int bi = 0;
#pragma unroll
    for (int k = 0; k < KPT; ++k) {
      float dx = px[k] - cx;
      float dy = py[k] - cy;
      float dz = pz[k] - cz;
      float d = (dx * dx + dy * dy) + dz * dz;   // numpy order, no FMA
      float od = sdist[k * THREADS + t];
      float nd = od < d ? od : d;                // jnp.minimum
      sdist[k * THREADS + t] = nd;
      if (nd > bd) { bd = nd; bi = base + t + k * THREADS; }  // k asc => first-max
    }

    // ---- two-phase wave reduce via DPP: max distbits, then max ~idx ----
    const uint32_t mydb = __float_as_uint(bd);   // bd >= 0 => order-preserving
    const uint32_t db = wave_max_bcast(mydb);
    const uint32_t mk = wave_max_bcast((mydb == db) ? ~(uint32_t)bi : 0u);

    if (lane == 0) {
      sk[par][w] = ((unsigned long long)db << 32) |
                   ((unsigned long long)tag << TAG_SHIFT) |
                   (unsigned long long)(mk & IDX_MASK);
    }
    __syncthreads();   // the only barrier per step

    // ---- every wave: reduce the 16 wave combos (two-phase u32 DPP) ----
    unsigned long long sv = (lane < NWAVES) ? sk[par][lane] : 0ull;
    uint32_t ghi = (uint32_t)(sv >> 32);
    const uint32_t gdb = wave_max_bcast(ghi);
    const uint32_t gmk = wave_max_bcast((lane < NWAVES && ghi == gdb)
                                        ? ((uint32_t)sv & IDX_MASK) : 0u);

    uint64_t* line = line_base + (size_t)par * LINE_U64;
    if (t == 0) {
      // Relaxed is safe: combo self-contained; parity+tag protocol guarantees
      // no reader of this slot's previous step is still in flight.
      unsigned long long combo = ((unsigned long long)gdb << 32) |
                                 ((unsigned long long)tag << TAG_SHIFT) |
                                 (unsigned long long)gmk;
      __hip_atomic_store(&line[g], combo, __ATOMIC_RELAXED,
                         __HIP_MEMORY_SCOPE_AGENT);
    }
    if (g == 0 && t == 0) {    // off the critical path (after publish)
      out_idx[(size_t)b * S + s] = (float)cur;
      size_t o = ((size_t)b * S + s) * 3;
      out_pts[o + 0] = cx; out_pts[o + 1] = cy; out_pts[o + 2] = cz;
    }

    // ---- all waves poll the 8 group records (relaxed, self-contained) ----
    unsigned long long v = 0;
    int done = (lane < GROUPS) ? 0 : 1;
    while (!__all(done)) {
      if (!done) {
        v = __hip_atomic_load(&line[lane], __ATOMIC_RELAXED,
                              __HIP_MEMORY_SCOPE_AGENT);
        done = (((uint32_t)(v >> TAG_SHIFT) & TAG_MASK) == tag);
      }
      if (!__all(done)) __builtin_amdgcn_s_sleep(1);
    }
    uint32_t fhi = (uint32_t)(v >> 32);
    const uint32_t fdb = wave_max_bcast(fhi);
    const uint32_t fmk = wave_max_bcast((fhi == fdb) ? ((uint32_t)v & IDX_MASK) : 0u);

    // ---- winner index + coords (uniform-address load, one txn per wave) ----
    cur = (int)((~fmk) & IDX_MASK);
    const float* wp = pb + (size_t)cur * 3;
    cx = wp[0]; cy = wp[1]; cz = wp[2];
  }
}

extern "C" void kernel_launch(void* const* d_in, const int* in_sizes, int n_in,
                              void* d_out, int out_size, void* d_ws, size_t ws_size,
                              hipStream_t stream) {
  const float* points = (const float*)d_in[0];
  const int* nsamples = (const int*)d_in[1];
  // d_in[2] = kd_depth: acceleration parameter only; math identical. Ignored.

  const int P = in_sizes[0] / (BATCHES * 3);   // 131072

  uint64_t* cand = (uint64_t*)d_ws;   // [32][2][16 u64] = 8KB

  hipLaunchKernelGGL(init_ws_kernel, dim3(1), dim3(BATCHES * 2 * LINE_U64),
                     0, stream, cand);

  dim3 grid(GROUPS * BATCHES);
  hipLaunchKernelGGL(fps_kernel, grid, dim3(THREADS), 0, stream,
                     points, nsamples, (float*)d_out, cand, P);
}